// Round 2
// baseline (530.024 us; speedup 1.0000x reference)
//
#include <hip/hip_runtime.h>
#include <math.h>

#define BATCH 8
#define CIN 256
#define S 1024       // 32*32 tokens
#define KDIM 512
#define NH 8
#define HD 64        // head dim (k and v)

// ---------------------------------------------------------------------------
// Fused QKV projection GEMM.
// out_t[b][h][s][d] = sum_c in[b][c][s] * w[h*64+d][c] + bias   (per q/k/v)
// in: (B, CIN, S) contig in s;  w: (512, CIN) contig in c;  out: (B,NH,S,HD)
// grid (S/128, 12, B), block 256. BM=BN=128, BK=32; 8x8/thread as 2x2 float4
// micro-tiles at stride 64 (keeps all hot LDS reads <=2-way).
// ---------------------------------------------------------------------------
__global__ __launch_bounds__(256)
void proj_fused_kernel(const float* __restrict__ in,
                       const float* __restrict__ q_w, const float* __restrict__ q_b,
                       const float* __restrict__ k_w, const float* __restrict__ k_b,
                       const float* __restrict__ v_w, const float* __restrict__ v_b,
                       float* __restrict__ q_t, float* __restrict__ k_t,
                       float* __restrict__ v_t)
{
    __shared__ float As[32][128];   // [c][s]
    __shared__ float Ws[32][132];   // [c][n] pad 132: f4-aligned, 2-way reads

    const int s0 = blockIdx.x * 128;
    const int yy = blockIdx.y;            // 0..11
    const int b  = blockIdx.z;
    const int which = yy >> 2;            // 0=q, 1=k, 2=v
    const int n0 = (yy & 3) * 128;        // within this projection's 512 cols

    const float* w  = (which == 0) ? q_w : (which == 1) ? k_w : v_w;
    const float* bs = (which == 0) ? q_b : (which == 1) ? k_b : v_b;
    float* outp     = (which == 0) ? q_t : (which == 1) ? k_t : v_t;

    const int tid = threadIdx.x;
    const int ts = tid >> 4;              // 0..15 row group
    const int tn = tid & 15;              // 0..15 col group

    const float* inb = in + (size_t)b * CIN * S;
    float acc[2][2][4][4] = {};           // [rowgrp][colgrp][i][j]

    for (int c0 = 0; c0 < CIN; c0 += 32) {
        // A tile: 32c x 128s = 1024 float4, 4/thread, coalesced
        #pragma unroll
        for (int i = 0; i < 4; ++i) {
            const int f4 = tid + i * 256;
            const int cc = f4 >> 5, s4 = f4 & 31;
            *(float4*)&As[cc][s4 * 4] =
                *(const float4*)&inb[(size_t)(c0 + cc) * S + s0 + s4 * 4];
        }
        // W tile: 128n x 32c, scatter-transpose into Ws[c][n]
        #pragma unroll
        for (int i = 0; i < 4; ++i) {
            const int f4 = tid + i * 256;
            const int nn = f4 >> 3, c4 = f4 & 7;
            const float4 wv = *(const float4*)&w[(size_t)(n0 + nn) * CIN + c0 + c4 * 4];
            Ws[c4 * 4 + 0][nn] = wv.x;
            Ws[c4 * 4 + 1][nn] = wv.y;
            Ws[c4 * 4 + 2][nn] = wv.z;
            Ws[c4 * 4 + 3][nn] = wv.w;
        }
        __syncthreads();
        #pragma unroll
        for (int c = 0; c < 32; ++c) {
            const float4 a0 = *(const float4*)&As[c][ts * 4];
            const float4 a1 = *(const float4*)&As[c][ts * 4 + 64];
            const float4 w0 = *(const float4*)&Ws[c][tn * 4];
            const float4 w1 = *(const float4*)&Ws[c][tn * 4 + 64];
            const float av[2][4] = {{a0.x, a0.y, a0.z, a0.w}, {a1.x, a1.y, a1.z, a1.w}};
            const float wv[2][4] = {{w0.x, w0.y, w0.z, w0.w}, {w1.x, w1.y, w1.z, w1.w}};
            #pragma unroll
            for (int rg = 0; rg < 2; ++rg)
                #pragma unroll
                for (int cg = 0; cg < 2; ++cg)
                    #pragma unroll
                    for (int i = 0; i < 4; ++i)
                        #pragma unroll
                        for (int j = 0; j < 4; ++j)
                            acc[rg][cg][i][j] += av[rg][i] * wv[cg][j];
        }
        __syncthreads();
    }

    // Epilogue: col group cg covers n = n0 + cg*64 + tn*4 (+0..3); since n0 and
    // cg*64 are multiples of 64, head h = n>>6 and d = tn*4+j exactly.
    #pragma unroll
    for (int cg = 0; cg < 2; ++cg) {
        const int ncol = n0 + cg * 64 + tn * 4;
        const int h = ncol >> 6;
        const int d = tn * 4;
        const float4 bias4 = *(const float4*)&bs[ncol];
        float* po = outp + ((size_t)b * NH + h) * S * HD;
        #pragma unroll
        for (int rg = 0; rg < 2; ++rg) {
            #pragma unroll
            for (int i = 0; i < 4; ++i) {
                const int srow = s0 + rg * 64 + ts * 4 + i;
                float4 o;
                o.x = acc[rg][cg][i][0] + bias4.x;
                o.y = acc[rg][cg][i][1] + bias4.y;
                o.z = acc[rg][cg][i][2] + bias4.z;
                o.w = acc[rg][cg][i][3] + bias4.w;
                *(float4*)&po[(size_t)srow * HD + d] = o;   // 16 lanes: 256B contig
            }
        }
    }
}

// ---------------------------------------------------------------------------
// Flash-style causal attention, fp32.
// block = (64-row q-tile, head, batch); 256 threads = 16 row-groups x 16 key-
// groups; each thread: 4 rows x 4 keys (QK) / 4 rows x 4 dims (PV).
// K staged transposed (Kt[d][j]); online softmax via 16-lane shfl reductions.
// Output written as out[b][h*64+d][s] (reference's transpose+reshape).
// ---------------------------------------------------------------------------
__global__ __launch_bounds__(256)
void attn_kernel(const float* __restrict__ q_t, const float* __restrict__ k_t,
                 const float* __restrict__ v_t, float* __restrict__ out)
{
    __shared__ float Qs[64][68];   // [r][d]
    __shared__ float Kt[64][68];   // [d][j] transposed K
    __shared__ float Vs[64][64];   // [j][d]
    __shared__ float Ps[64][68];   // P tile; reused for output transpose

    const int qt = (int)gridDim.x - 1 - (int)blockIdx.x;  // heavy tiles first
    const int h  = blockIdx.y;
    const int b  = blockIdx.z;
    const int tid = threadIdx.x;
    const int s0 = qt * 64;

    const size_t bh = (size_t)b * NH + h;
    const float* qp = q_t + bh * S * HD;
    const float* kp = k_t + bh * S * HD;
    const float* vp = v_t + bh * S * HD;

    // Q tile 64x64: 1024 float4, 4/thread (consumed after the in-loop barrier)
    #pragma unroll
    for (int i = 0; i < 4; ++i) {
        const int f4 = tid + i * 256;
        const int r = f4 >> 4, d4 = f4 & 15;
        *(float4*)&Qs[r][d4 * 4] = *(const float4*)&qp[(size_t)(s0 + r) * HD + d4 * 4];
    }

    const int tr = tid >> 4;       // 0..15 -> rows tr*4 .. tr*4+3
    const int kg = tid & 15;       // 0..15 -> keys/dims kg*4 .. kg*4+3
    const int r0 = tr * 4;

    float m[4] = {-1e30f, -1e30f, -1e30f, -1e30f};
    float l[4] = {0.f, 0.f, 0.f, 0.f};
    float O[4][4] = {};

    const int ntiles = qt + 1;
    for (int kt = 0; kt < ntiles; ++kt) {
        __syncthreads();           // prev PV done (and Qs ready on kt=0)
        // stage K (transposed) + V: 64x64 each; 1024 float4 total, 4/thread
        #pragma unroll
        for (int i = 0; i < 4; ++i) {
            const int f4 = tid + i * 256;
            const int j = f4 >> 4, d4 = f4 & 15;
            const size_t row = (size_t)(kt * 64 + j) * HD;
            const float4 kv = *(const float4*)&kp[row + d4 * 4];
            Kt[d4 * 4 + 0][j] = kv.x;
            Kt[d4 * 4 + 1][j] = kv.y;
            Kt[d4 * 4 + 2][j] = kv.z;
            Kt[d4 * 4 + 3][j] = kv.w;
            *(float4*)&Vs[j][d4 * 4] = *(const float4*)&vp[row + d4 * 4];
        }
        __syncthreads();

        // ---- scores: 4 rows x 4 keys ----
        float sc[4][4] = {};
        #pragma unroll
        for (int d4 = 0; d4 < 16; ++d4) {
            float qv[4][4];
            #pragma unroll
            for (int rr = 0; rr < 4; ++rr) {
                const float4 t = *(const float4*)&Qs[r0 + rr][d4 * 4];
                qv[rr][0] = t.x; qv[rr][1] = t.y; qv[rr][2] = t.z; qv[rr][3] = t.w;
            }
            #pragma unroll
            for (int e = 0; e < 4; ++e) {
                const float4 kf = *(const float4*)&Kt[d4 * 4 + e][kg * 4];
                #pragma unroll
                for (int rr = 0; rr < 4; ++rr) {
                    sc[rr][0] += qv[rr][e] * kf.x;
                    sc[rr][1] += qv[rr][e] * kf.y;
                    sc[rr][2] += qv[rr][e] * kf.z;
                    sc[rr][3] += qv[rr][e] * kf.w;
                }
            }
        }

        // ---- scale + causal mask (diagonal tile only) ----
        const bool diag = (kt == qt);
        float tmax[4] = {-1e30f, -1e30f, -1e30f, -1e30f};
        #pragma unroll
        for (int rr = 0; rr < 4; ++rr) {
            const int r = s0 + r0 + rr;
            #pragma unroll
            for (int jj = 0; jj < 4; ++jj) {
                const int key = kt * 64 + kg * 4 + jj;
                float v = sc[rr][jj] * 0.125f;            // 1/sqrt(64)
                if (diag && key > r) v = -1e30f;
                sc[rr][jj] = v;
                tmax[rr] = fmaxf(tmax[rr], v);
            }
        }
        #pragma unroll
        for (int mk = 1; mk < 16; mk <<= 1)
            #pragma unroll
            for (int rr = 0; rr < 4; ++rr)
                tmax[rr] = fmaxf(tmax[rr], __shfl_xor(tmax[rr], mk));

        float sscale[4], tsum[4];
        #pragma unroll
        for (int rr = 0; rr < 4; ++rr) {
            const float mn = fmaxf(m[rr], tmax[rr]);
            sscale[rr] = __expf(m[rr] - mn);
            float ssum = 0.f;
            #pragma unroll
            for (int jj = 0; jj < 4; ++jj) {
                const float p = __expf(sc[rr][jj] - mn);
                sc[rr][jj] = p;
                ssum += p;
            }
            tsum[rr] = ssum;
            m[rr] = mn;
        }
        #pragma unroll
        for (int mk = 1; mk < 16; mk <<= 1)
            #pragma unroll
            for (int rr = 0; rr < 4; ++rr)
                tsum[rr] += __shfl_xor(tsum[rr], mk);

        #pragma unroll
        for (int rr = 0; rr < 4; ++rr) {
            l[rr] = l[rr] * sscale[rr] + tsum[rr];
            #pragma unroll
            for (int j = 0; j < 4; ++j) O[rr][j] *= sscale[rr];
            #pragma unroll
            for (int jj = 0; jj < 4; ++jj) Ps[r0 + rr][kg * 4 + jj] = sc[rr][jj];
        }
        __syncthreads();

        // ---- P @ V: 4 rows x 4 dims ----
        #pragma unroll
        for (int j4 = 0; j4 < 16; ++j4) {
            float pv[4][4];
            #pragma unroll
            for (int rr = 0; rr < 4; ++rr) {
                const float4 t = *(const float4*)&Ps[r0 + rr][j4 * 4];
                pv[rr][0] = t.x; pv[rr][1] = t.y; pv[rr][2] = t.z; pv[rr][3] = t.w;
            }
            #pragma unroll
            for (int e = 0; e < 4; ++e) {
                const float4 vf = *(const float4*)&Vs[j4 * 4 + e][kg * 4];
                #pragma unroll
                for (int rr = 0; rr < 4; ++rr) {
                    O[rr][0] += pv[rr][e] * vf.x;
                    O[rr][1] += pv[rr][e] * vf.y;
                    O[rr][2] += pv[rr][e] * vf.z;
                    O[rr][3] += pv[rr][e] * vf.w;
                }
            }
        }
    }

    // ---- normalize, transpose through LDS, coalesced store ----
    __syncthreads();               // all PV reads of Ps done
    #pragma unroll
    for (int rr = 0; rr < 4; ++rr) {
        const float inv = 1.0f / l[rr];
        #pragma unroll
        for (int jj = 0; jj < 4; ++jj)
            Ps[r0 + rr][kg * 4 + jj] = O[rr][jj] * inv;
    }
    __syncthreads();
    float* op = out + ((size_t)b * KDIM + (size_t)h * HD) * S + s0;
    #pragma unroll
    for (int i = 0; i < 16; ++i) {
        const int lin = i * 256 + tid;
        const int d = lin >> 6, srow = lin & 63;   // 64 lanes -> contig s
        op[(size_t)d * S + srow] = Ps[srow][d];
    }
}

extern "C" void kernel_launch(void* const* d_in, const int* in_sizes, int n_in,
                              void* d_out, int out_size, void* d_ws, size_t ws_size,
                              hipStream_t stream)
{
    const float* input = (const float*)d_in[0];
    const float* q_w   = (const float*)d_in[1];
    const float* q_b   = (const float*)d_in[2];
    const float* k_w   = (const float*)d_in[3];
    const float* k_b   = (const float*)d_in[4];
    const float* v_w   = (const float*)d_in[5];
    const float* v_b   = (const float*)d_in[6];
    float* out = (float*)d_out;

    const size_t per = (size_t)BATCH * NH * S * HD;   // 4,194,304 floats = 16 MB
    float* q_t = (float*)d_ws;
    float* k_t = q_t + per;
    float* v_t = k_t + per;

    proj_fused_kernel<<<dim3(S / 128, 12, BATCH), 256, 0, stream>>>(
        input, q_w, q_b, k_w, k_b, v_w, v_b, q_t, k_t, v_t);

    attn_kernel<<<dim3(S / 64, NH, BATCH), 256, 0, stream>>>(q_t, k_t, v_t, out);
}

// Round 6
// 248.023 us; speedup vs baseline: 2.1370x; 2.1370x over previous
//
#include <hip/hip_runtime.h>
#include <math.h>

#define BATCH 8
#define CIN 256
#define S 1024       // 32*32 tokens
#define KDIM 512
#define NH 8
#define HD 64        // head dim

typedef float  f32x4  __attribute__((ext_vector_type(4)));
typedef short  bf16x8 __attribute__((ext_vector_type(8)));

static __device__ __forceinline__ unsigned short f2bf(float x) {
    unsigned u = __builtin_bit_cast(unsigned, x);
    u += 0x7FFFu + ((u >> 16) & 1u);          // RNE
    return (unsigned short)(u >> 16);
}
static __device__ __forceinline__ float bf2f(unsigned short v) {
    unsigned u = ((unsigned)v) << 16;
    return __builtin_bit_cast(float, u);
}
static __device__ __forceinline__ f32x4 mfma16(bf16x8 a, bf16x8 b, f32x4 c) {
    return __builtin_amdgcn_mfma_f32_16x16x32_bf16(a, b, c, 0, 0, 0);
}

// ---------------------------------------------------------------------------
// Fused QKV projection GEMM (fp32 compute — validated structure, round-2 run).
// Epilogue emits q,k,v ALL as bf16 hi+lo pairs (for bf16x3 MFMA attention).
// Layouts: [b][h][s][d] contiguous in d.
// ---------------------------------------------------------------------------
__global__ __launch_bounds__(256)
void proj_fused_kernel(const float* __restrict__ in,
                       const float* __restrict__ q_w, const float* __restrict__ q_b,
                       const float* __restrict__ k_w, const float* __restrict__ k_b,
                       const float* __restrict__ v_w, const float* __restrict__ v_b,
                       unsigned short* __restrict__ qhi, unsigned short* __restrict__ qlo,
                       unsigned short* __restrict__ khi, unsigned short* __restrict__ klo,
                       unsigned short* __restrict__ vhi, unsigned short* __restrict__ vlo)
{
    __shared__ float As[32][128];   // [c][s]
    __shared__ float Ws[32][132];   // [c][n]

    const int s0 = blockIdx.x * 128;
    const int yy = blockIdx.y;            // 0..11
    const int b  = blockIdx.z;
    const int which = yy >> 2;            // 0=q, 1=k, 2=v
    const int n0 = (yy & 3) * 128;

    const float* w  = (which == 0) ? q_w : (which == 1) ? k_w : v_w;
    const float* bs = (which == 0) ? q_b : (which == 1) ? k_b : v_b;
    unsigned short* ph_g = (which == 0) ? qhi : (which == 1) ? khi : vhi;
    unsigned short* pl_g = (which == 0) ? qlo : (which == 1) ? klo : vlo;

    const int tid = threadIdx.x;
    const int ts = tid >> 4;
    const int tn = tid & 15;

    const float* inb = in + (size_t)b * CIN * S;
    float acc[2][2][4][4] = {};

    for (int c0 = 0; c0 < CIN; c0 += 32) {
        #pragma unroll
        for (int i = 0; i < 4; ++i) {
            const int f4 = tid + i * 256;
            const int cc = f4 >> 5, s4 = f4 & 31;
            *(float4*)&As[cc][s4 * 4] =
                *(const float4*)&inb[(size_t)(c0 + cc) * S + s0 + s4 * 4];
        }
        #pragma unroll
        for (int i = 0; i < 4; ++i) {
            const int f4 = tid + i * 256;
            const int nn = f4 >> 3, c4 = f4 & 7;
            const float4 wv = *(const float4*)&w[(size_t)(n0 + nn) * CIN + c0 + c4 * 4];
            Ws[c4 * 4 + 0][nn] = wv.x;
            Ws[c4 * 4 + 1][nn] = wv.y;
            Ws[c4 * 4 + 2][nn] = wv.z;
            Ws[c4 * 4 + 3][nn] = wv.w;
        }
        __syncthreads();
        #pragma unroll
        for (int c = 0; c < 32; ++c) {
            const float4 a0 = *(const float4*)&As[c][ts * 4];
            const float4 a1 = *(const float4*)&As[c][ts * 4 + 64];
            const float4 w0 = *(const float4*)&Ws[c][tn * 4];
            const float4 w1 = *(const float4*)&Ws[c][tn * 4 + 64];
            const float av[2][4] = {{a0.x, a0.y, a0.z, a0.w}, {a1.x, a1.y, a1.z, a1.w}};
            const float wv[2][4] = {{w0.x, w0.y, w0.z, w0.w}, {w1.x, w1.y, w1.z, w1.w}};
            #pragma unroll
            for (int rg = 0; rg < 2; ++rg)
                #pragma unroll
                for (int cg = 0; cg < 2; ++cg)
                    #pragma unroll
                    for (int i = 0; i < 4; ++i)
                        #pragma unroll
                        for (int j = 0; j < 4; ++j)
                            acc[rg][cg][i][j] += av[rg][i] * wv[cg][j];
        }
        __syncthreads();
    }

    #pragma unroll
    for (int cg = 0; cg < 2; ++cg) {
        const int ncol = n0 + cg * 64 + tn * 4;   // n0, cg*64 are 64-multiples
        const int h = ncol >> 6;
        const int d0 = tn * 4;
        const float4 bias4 = *(const float4*)&bs[ncol];
        const float bb[4] = {bias4.x, bias4.y, bias4.z, bias4.w};
        const size_t obase = ((size_t)b * NH + h) * S * HD;
        #pragma unroll
        for (int rg = 0; rg < 2; ++rg) {
            #pragma unroll
            for (int i = 0; i < 4; ++i) {
                const int srow = s0 + rg * 64 + ts * 4 + i;
                ushort4 hv, lv;
                {
                    const float x0 = acc[rg][cg][i][0] + bb[0];
                    const float x1 = acc[rg][cg][i][1] + bb[1];
                    const float x2 = acc[rg][cg][i][2] + bb[2];
                    const float x3 = acc[rg][cg][i][3] + bb[3];
                    unsigned short h0 = f2bf(x0); lv.x = f2bf(x0 - bf2f(h0)); hv.x = h0;
                    unsigned short h1 = f2bf(x1); lv.y = f2bf(x1 - bf2f(h1)); hv.y = h1;
                    unsigned short h2 = f2bf(x2); lv.z = f2bf(x2 - bf2f(h2)); hv.z = h2;
                    unsigned short h3 = f2bf(x3); lv.w = f2bf(x3 - bf2f(h3)); hv.w = h3;
                }
                *(ushort4*)&ph_g[obase + (size_t)srow * HD + d0] = hv;
                *(ushort4*)&pl_g[obase + (size_t)srow * HD + d0] = lv;
            }
        }
    }
}

// ---------------------------------------------------------------------------
// MFMA flash attention — bf16x3 split on ALL matmuls (QK^T and PV), fp32
// softmax/accum. Predicted absmax == fp32 baseline (dropped terms ~2^-17).
// block = 256 thr = 4 waves; wave w owns q-rows s0+w*16..+15. KV tile = 64.
// LDS: Khi/Klo [64 rows][128B] XOR16-swizzled; VtHi/VtLo [d][k] swizzled;
// per-wave Phi/Plo [16 rows][128B]. Output: out[b][h*64+d][s] fp32.
// ---------------------------------------------------------------------------
#define KHI_OFF  0
#define KLO_OFF  8192
#define VTHI_OFF 16384
#define VTLO_OFF 24576
#define PSHI_OFF 32768   // + w*2048
#define PSLO_OFF 40960   // + w*2048

__global__ __launch_bounds__(256)
void attn_mfma_kernel(const unsigned short* __restrict__ qhi_g,
                      const unsigned short* __restrict__ qlo_g,
                      const unsigned short* __restrict__ khi_g,
                      const unsigned short* __restrict__ klo_g,
                      const unsigned short* __restrict__ vhi_g,
                      const unsigned short* __restrict__ vlo_g,
                      float* __restrict__ out)
{
    __shared__ __attribute__((aligned(16))) char smem[49152];

    const int qt = 15 - (int)blockIdx.x;     // heavy tiles first
    const int h  = blockIdx.y;
    const int b  = blockIdx.z;
    const int tid = threadIdx.x;
    const int w  = tid >> 6;                 // wave 0..3
    const int l  = tid & 63;
    const int lg = l >> 4;                   // 0..3
    const int lm = l & 15;
    const int s0 = qt * 64;

    const size_t base = ((size_t)b * NH + h) * S * HD;

    // Q fragments (A operand): row = s0 + w*16 + lm, k = ks*32 + lg*8 (+0..7)
    bf16x8 qh[2], ql[2];
    {
        const size_t qoff = base + (size_t)(s0 + w * 16 + lm) * HD + lg * 8;
        qh[0] = *(const bf16x8*)(qhi_g + qoff);
        qh[1] = *(const bf16x8*)(qhi_g + qoff + 32);
        ql[0] = *(const bf16x8*)(qlo_g + qoff);
        ql[1] = *(const bf16x8*)(qlo_g + qoff + 32);
    }

    float m[4] = {-1e30f, -1e30f, -1e30f, -1e30f};
    float lsum[4] = {0.f, 0.f, 0.f, 0.f};
    f32x4 accO[4];
    #pragma unroll
    for (int dt = 0; dt < 4; ++dt) accO[dt] = (f32x4){0.f, 0.f, 0.f, 0.f};

    for (int kt = 0; kt <= qt; ++kt) {
        __syncthreads();                      // all waves done with prev tile
        // ---- stage Khi/Klo (swizzled rows) + Vhi/Vlo transposed ----
        {
            const size_t kbase = base + (size_t)(kt * 64) * HD;
            #pragma unroll
            for (int i = 0; i < 2; ++i) {
                const int c = tid + i * 256;
                const int krow = c >> 3;
                const int d0 = (c & 7) * 8;
                const int swzk = (krow & 7) << 4;
                const size_t goff = kbase + (size_t)krow * HD + d0;
                const uint4 hk = *(const uint4*)(khi_g + goff);
                const uint4 lk = *(const uint4*)(klo_g + goff);
                *(uint4*)(smem + KHI_OFF + krow * 128 + ((d0 * 2) ^ swzk)) = hk;
                *(uint4*)(smem + KLO_OFF + krow * 128 + ((d0 * 2) ^ swzk)) = lk;
                const uint4 hv = *(const uint4*)(vhi_g + goff);
                const uint4 lv = *(const uint4*)(vlo_g + goff);
                const unsigned short* he = (const unsigned short*)&hv;
                const unsigned short* le = (const unsigned short*)&lv;
                #pragma unroll
                for (int j = 0; j < 8; ++j) {
                    const int d = d0 + j;
                    const int swzv = (((d >> 3) ^ d) & 7) << 4;
                    const int boff = d * 128 + ((2 * krow) ^ swzv);
                    *(unsigned short*)(smem + VTHI_OFF + boff) = he[j];
                    *(unsigned short*)(smem + VTLO_OFF + boff) = le[j];
                }
            }
        }
        __syncthreads();

        // ---- QK^T: bf16x3 (QhiKhi + QloKhi + QhiKlo) ----
        f32x4 sc[4];
        __builtin_amdgcn_s_setprio(1);        // T5: favor MFMA-issuing wave
        #pragma unroll
        for (int kb = 0; kb < 4; ++kb) {
            f32x4 a = (f32x4){0.f, 0.f, 0.f, 0.f};
            #pragma unroll
            for (int ks = 0; ks < 2; ++ks) {
                const int row = kb * 16 + lm;
                const int cb = 64 * ks + 16 * lg;
                const int swz = (row & 7) << 4;
                const bf16x8 bh_ = *(const bf16x8*)(smem + KHI_OFF + row * 128 + (cb ^ swz));
                const bf16x8 bl_ = *(const bf16x8*)(smem + KLO_OFF + row * 128 + (cb ^ swz));
                a = mfma16(qh[ks], bh_, a);
                a = mfma16(ql[ks], bh_, a);
                a = mfma16(qh[ks], bl_, a);
            }
            sc[kb] = a;
        }
        __builtin_amdgcn_s_setprio(0);

        // ---- scale + causal mask + online softmax (D layout: row=lg*4+r, col=lm) ----
        const bool diag = (kt == qt);
        float tmax[4] = {-1e30f, -1e30f, -1e30f, -1e30f};
        #pragma unroll
        for (int kb = 0; kb < 4; ++kb) {
            const int key = kt * 64 + kb * 16 + lm;
            #pragma unroll
            for (int r = 0; r < 4; ++r) {
                float v = sc[kb][r] * 0.125f;       // 1/sqrt(64)
                const int row = s0 + w * 16 + lg * 4 + r;
                if (diag && key > row) v = -1e30f;
                sc[kb][r] = v;
                tmax[r] = fmaxf(tmax[r], v);
            }
        }
        #pragma unroll
        for (int mk = 1; mk < 16; mk <<= 1)
            #pragma unroll
            for (int r = 0; r < 4; ++r)
                tmax[r] = fmaxf(tmax[r], __shfl_xor(tmax[r], mk));

        float tsum[4], sscale[4];
        #pragma unroll
        for (int r = 0; r < 4; ++r) {
            const float mn = fmaxf(m[r], tmax[r]);
            sscale[r] = __expf(m[r] - mn);
            m[r] = mn;
            float ssum = 0.f;
            #pragma unroll
            for (int kb = 0; kb < 4; ++kb) {
                const float p = __expf(sc[kb][r] - mn);
                sc[kb][r] = p;
                ssum += p;
            }
            tsum[r] = ssum;
        }
        #pragma unroll
        for (int mk = 1; mk < 16; mk <<= 1)
            #pragma unroll
            for (int r = 0; r < 4; ++r)
                tsum[r] += __shfl_xor(tsum[r], mk);

        #pragma unroll
        for (int r = 0; r < 4; ++r) {
            lsum[r] = lsum[r] * sscale[r] + tsum[r];
            #pragma unroll
            for (int dt = 0; dt < 4; ++dt) accO[dt][r] *= sscale[r];
            const int r_loc = lg * 4 + r;
            const int swz = (r_loc & 7) << 4;
            #pragma unroll
            for (int kb = 0; kb < 4; ++kb) {
                const float p = sc[kb][r];
                const unsigned short phq = f2bf(p);
                const unsigned short plq = f2bf(p - bf2f(phq));
                const int boff = (w << 11) + r_loc * 128 + ((2 * (kb * 16 + lm)) ^ swz);
                *(unsigned short*)(smem + PSHI_OFF + boff) = phq;
                *(unsigned short*)(smem + PSLO_OFF + boff) = plq;
            }
        }

        // ---- P @ V: bf16x3 (PhiVhi + PloVhi + PhiVlo) ----
        __builtin_amdgcn_s_setprio(1);        // T5
        #pragma unroll
        for (int ks = 0; ks < 2; ++ks) {
            const int cb = 64 * ks + 16 * lg;
            const int swzp = (lm & 7) << 4;
            const bf16x8 phi = *(const bf16x8*)(smem + PSHI_OFF + (w << 11) + lm * 128 + (cb ^ swzp));
            const bf16x8 plo = *(const bf16x8*)(smem + PSLO_OFF + (w << 11) + lm * 128 + (cb ^ swzp));
            #pragma unroll
            for (int dt = 0; dt < 4; ++dt) {
                const int d = dt * 16 + lm;
                const int swzv = (((d >> 3) ^ d) & 7) << 4;
                const bf16x8 vh_ = *(const bf16x8*)(smem + VTHI_OFF + d * 128 + (cb ^ swzv));
                const bf16x8 vl_ = *(const bf16x8*)(smem + VTLO_OFF + d * 128 + (cb ^ swzv));
                accO[dt] = mfma16(phi, vh_, accO[dt]);
                accO[dt] = mfma16(plo, vh_, accO[dt]);
                accO[dt] = mfma16(phi, vl_, accO[dt]);
            }
        }
        __builtin_amdgcn_s_setprio(0);
    }

    // ---- normalize, LDS transpose (reuse staging region), coalesced store ----
    __syncthreads();
    float* Ot = (float*)smem;                 // [64][66] fp32 = 16896 B
    float invl[4];
    #pragma unroll
    for (int r = 0; r < 4; ++r) invl[r] = 1.0f / lsum[r];
    #pragma unroll
    for (int dt = 0; dt < 4; ++dt)
        #pragma unroll
        for (int r = 0; r < 4; ++r)
            Ot[(w * 16 + lg * 4 + r) * 66 + dt * 16 + lm] = accO[dt][r] * invl[r];
    __syncthreads();
    float* op = out + ((size_t)b * KDIM + (size_t)h * HD) * S + s0;
    #pragma unroll
    for (int i = 0; i < 16; ++i) {
        const int lin = tid + i * 256;
        const int d = lin >> 6, s = lin & 63;
        op[(size_t)d * S + s] = Ot[s * 66 + d];
    }
}

extern "C" void kernel_launch(void* const* d_in, const int* in_sizes, int n_in,
                              void* d_out, int out_size, void* d_ws, size_t ws_size,
                              hipStream_t stream)
{
    const float* input = (const float*)d_in[0];
    const float* q_w   = (const float*)d_in[1];
    const float* q_b   = (const float*)d_in[2];
    const float* k_w   = (const float*)d_in[3];
    const float* k_b   = (const float*)d_in[4];
    const float* v_w   = (const float*)d_in[5];
    const float* v_b   = (const float*)d_in[6];
    float* out = (float*)d_out;

    const size_t per = (size_t)BATCH * NH * S * HD;   // 4,194,304 elems
    unsigned short* qhi = (unsigned short*)d_ws;
    unsigned short* qlo = qhi + per;
    unsigned short* khi = qlo + per;
    unsigned short* klo = khi + per;
    unsigned short* vhi = klo + per;
    unsigned short* vlo = vhi + per;                  // total 48 MB

    proj_fused_kernel<<<dim3(S / 128, 12, BATCH), 256, 0, stream>>>(
        input, q_w, q_b, k_w, k_b, v_w, v_b, qhi, qlo, khi, klo, vhi, vlo);

    attn_mfma_kernel<<<dim3(S / 64, NH, BATCH), 256, 0, stream>>>(
        qhi, qlo, khi, klo, vhi, vlo, out);
}

// Round 8
// 205.572 us; speedup vs baseline: 2.5783x; 1.2065x over previous
//
#include <hip/hip_runtime.h>
#include <math.h>

#define BATCH 8
#define CIN 256
#define S 1024       // 32*32 tokens
#define KDIM 512
#define NH 8
#define HD 64        // head dim

typedef float  f32x4  __attribute__((ext_vector_type(4)));
typedef short  bf16x8 __attribute__((ext_vector_type(8)));
typedef unsigned short u16x8 __attribute__((ext_vector_type(8)));

static __device__ __forceinline__ unsigned short f2bf(float x) {
    unsigned u = __builtin_bit_cast(unsigned, x);
    u += 0x7FFFu + ((u >> 16) & 1u);          // RNE
    return (unsigned short)(u >> 16);
}
static __device__ __forceinline__ float bf2f(unsigned short v) {
    unsigned u = ((unsigned)v) << 16;
    return __builtin_bit_cast(float, u);
}
static __device__ __forceinline__ f32x4 mfma16(bf16x8 a, bf16x8 b, f32x4 c) {
    return __builtin_amdgcn_mfma_f32_16x16x32_bf16(a, b, c, 0, 0, 0);
}

// ---------------------------------------------------------------------------
// MFMA QKV projection: C[m][n] = sum_c x[m][c]*w[n][c] + bias, bf16x3 split
// on both operands (~fp32 accuracy). M=8192 (b*s), N=1536 (q||k||v), K=256.
// grid (8 s-tiles, 12 n-tiles, B); 256 thr = 4 waves (2m x 2n), wave 64x64.
// LDS fragment-native layout [kgrp][row][8k] bf16: all ds accesses are
// 16-lane x 16B-stride (2-way, free). x converted+transposed during staging
// via coalesced scalar loads; w converted during staging (L2-resident).
// Outputs q/k/v as bf16 hi/lo pairs, layout [b][h][s][d].
// ---------------------------------------------------------------------------
#define PA_HI 0       // [4][128][8] ushort = 8192 B each
#define PA_LO 8192
#define PB_HI 16384
#define PB_LO 24576

__global__ __launch_bounds__(256)
void proj_mfma_kernel(const float* __restrict__ in,
                      const float* __restrict__ q_w, const float* __restrict__ q_b,
                      const float* __restrict__ k_w, const float* __restrict__ k_b,
                      const float* __restrict__ v_w, const float* __restrict__ v_b,
                      unsigned short* __restrict__ qhi, unsigned short* __restrict__ qlo,
                      unsigned short* __restrict__ khi, unsigned short* __restrict__ klo,
                      unsigned short* __restrict__ vhi, unsigned short* __restrict__ vlo)
{
    __shared__ __attribute__((aligned(16))) char smem[32768];

    const int s0  = blockIdx.x * 128;        // s-rows of this tile
    const int nt  = blockIdx.y;              // 0..11
    const int b   = blockIdx.z;
    const int p   = nt >> 2;                 // 0=q,1=k,2=v  (512/128 = 4 tiles)
    const int nb0 = (nt & 3) * 128;          // within-proj col base

    const float* w  = (p == 0) ? q_w : (p == 1) ? k_w : v_w;
    const float* bs = (p == 0) ? q_b : (p == 1) ? k_b : v_b;
    unsigned short* ph_g = (p == 0) ? qhi : (p == 1) ? khi : vhi;
    unsigned short* pl_g = (p == 0) ? qlo : (p == 1) ? klo : vlo;

    const int tid = threadIdx.x;
    const int wv  = tid >> 6;                // wave 0..3
    const int wm  = wv >> 1, wn = wv & 1;    // 2x2 wave grid
    const int l   = tid & 63;
    const int lg  = l >> 4;                  // 0..3 (k-group / acc row group)
    const int lm  = l & 15;                  // 0..15 (frag row / acc col)

    const float* inb = in + (size_t)b * CIN * S;

    f32x4 acc[4][4];
    #pragma unroll
    for (int mf = 0; mf < 4; ++mf)
        #pragma unroll
        for (int nf = 0; nf < 4; ++nf) acc[mf][nf] = (f32x4){0.f, 0.f, 0.f, 0.f};

    for (int c0 = 0; c0 < CIN; c0 += 32) {
        __syncthreads();                     // prev frag reads done
        // ---- stage A (x): cells (m, kgrp); 8 coalesced scalar f32 along s ----
        #pragma unroll
        for (int j = 0; j < 2; ++j) {
            const int cell = tid + j * 256;
            const int m  = cell & 127;
            const int kg = cell >> 7;        // 0..3
            const float* src = inb + (size_t)(c0 + kg * 8) * S + s0 + m;
            u16x8 hv, lv;
            #pragma unroll
            for (int e = 0; e < 8; ++e) {
                const float v = src[(size_t)e * S];
                const unsigned short h = f2bf(v);
                hv[e] = h;
                lv[e] = f2bf(v - bf2f(h));
            }
            const int idx = (kg * 1024 + m * 8) * 2;
            *(u16x8*)(smem + PA_HI + idx) = hv;
            *(u16x8*)(smem + PA_LO + idx) = lv;
        }
        // ---- stage B (w): cells (n, kgrp); 2 float4 (c contiguous) ----
        #pragma unroll
        for (int j = 0; j < 2; ++j) {
            const int cell = tid + j * 256;
            const int n  = cell & 127;
            const int kg = cell >> 7;
            const float* src = w + (size_t)(nb0 + n) * CIN + c0 + kg * 8;
            const float4 w0 = *(const float4*)src;
            const float4 w1 = *(const float4*)(src + 4);
            const float vv[8] = {w0.x, w0.y, w0.z, w0.w, w1.x, w1.y, w1.z, w1.w};
            u16x8 hv, lv;
            #pragma unroll
            for (int e = 0; e < 8; ++e) {
                const unsigned short h = f2bf(vv[e]);
                hv[e] = h;
                lv[e] = f2bf(vv[e] - bf2f(h));
            }
            const int idx = (kg * 1024 + n * 8) * 2;
            *(u16x8*)(smem + PB_HI + idx) = hv;
            *(u16x8*)(smem + PB_LO + idx) = lv;
        }
        __syncthreads();

        // ---- fragments + bf16x3 MFMA ----
        bf16x8 ah[4], al[4];
        #pragma unroll
        for (int mf = 0; mf < 4; ++mf) {
            const int idx = (lg * 1024 + (wm * 64 + mf * 16 + lm) * 8) * 2;
            ah[mf] = *(const bf16x8*)(smem + PA_HI + idx);
            al[mf] = *(const bf16x8*)(smem + PA_LO + idx);
        }
        __builtin_amdgcn_s_setprio(1);
        #pragma unroll
        for (int nf = 0; nf < 4; ++nf) {
            const int idx = (lg * 1024 + (wn * 64 + nf * 16 + lm) * 8) * 2;
            const bf16x8 bh = *(const bf16x8*)(smem + PB_HI + idx);
            const bf16x8 bl = *(const bf16x8*)(smem + PB_LO + idx);
            #pragma unroll
            for (int mf = 0; mf < 4; ++mf) {
                acc[mf][nf] = mfma16(ah[mf], bh, acc[mf][nf]);
                acc[mf][nf] = mfma16(al[mf], bh, acc[mf][nf]);
                acc[mf][nf] = mfma16(ah[mf], bl, acc[mf][nf]);
            }
        }
        __builtin_amdgcn_s_setprio(0);
    }

    // ---- epilogue: bias, hi/lo split, store (C: row=lg*4+r -> m, col=lm -> n) ----
    #pragma unroll
    for (int nf = 0; nf < 4; ++nf) {
        const int ncol = nb0 + wn * 64 + nf * 16 + lm;   // within-proj 0..511
        const int h = ncol >> 6, d = ncol & 63;
        const float bias = bs[ncol];
        const size_t hb = ((size_t)b * NH + h) * S * HD + d;
        #pragma unroll
        for (int mf = 0; mf < 4; ++mf) {
            #pragma unroll
            for (int r = 0; r < 4; ++r) {
                const int srow = s0 + wm * 64 + mf * 16 + lg * 4 + r;
                const float x = acc[mf][nf][r] + bias;
                const unsigned short hq = f2bf(x);
                const unsigned short lq = f2bf(x - bf2f(hq));
                ph_g[hb + (size_t)srow * HD] = hq;
                pl_g[hb + (size_t)srow * HD] = lq;
            }
        }
    }
}

// ---------------------------------------------------------------------------
// MFMA flash attention — UNCHANGED from the validated round-6 kernel.
// bf16x3 split on QK^T and PV, fp32 softmax/accum, XOR-swizzled LDS.
// ---------------------------------------------------------------------------
#define KHI_OFF  0
#define KLO_OFF  8192
#define VTHI_OFF 16384
#define VTLO_OFF 24576
#define PSHI_OFF 32768   // + w*2048
#define PSLO_OFF 40960   // + w*2048

__global__ __launch_bounds__(256)
void attn_mfma_kernel(const unsigned short* __restrict__ qhi_g,
                      const unsigned short* __restrict__ qlo_g,
                      const unsigned short* __restrict__ khi_g,
                      const unsigned short* __restrict__ klo_g,
                      const unsigned short* __restrict__ vhi_g,
                      const unsigned short* __restrict__ vlo_g,
                      float* __restrict__ out)
{
    __shared__ __attribute__((aligned(16))) char smem[49152];

    const int qt = 15 - (int)blockIdx.x;     // heavy tiles first
    const int h  = blockIdx.y;
    const int b  = blockIdx.z;
    const int tid = threadIdx.x;
    const int w  = tid >> 6;                 // wave 0..3
    const int l  = tid & 63;
    const int lg = l >> 4;                   // 0..3
    const int lm = l & 15;
    const int s0 = qt * 64;

    const size_t base = ((size_t)b * NH + h) * S * HD;

    // Q fragments (A operand): row = s0 + w*16 + lm, k = ks*32 + lg*8 (+0..7)
    bf16x8 qh[2], ql[2];
    {
        const size_t qoff = base + (size_t)(s0 + w * 16 + lm) * HD + lg * 8;
        qh[0] = *(const bf16x8*)(qhi_g + qoff);
        qh[1] = *(const bf16x8*)(qhi_g + qoff + 32);
        ql[0] = *(const bf16x8*)(qlo_g + qoff);
        ql[1] = *(const bf16x8*)(qlo_g + qoff + 32);
    }

    float m[4] = {-1e30f, -1e30f, -1e30f, -1e30f};
    float lsum[4] = {0.f, 0.f, 0.f, 0.f};
    f32x4 accO[4];
    #pragma unroll
    for (int dt = 0; dt < 4; ++dt) accO[dt] = (f32x4){0.f, 0.f, 0.f, 0.f};

    for (int kt = 0; kt <= qt; ++kt) {
        __syncthreads();                      // all waves done with prev tile
        // ---- stage Khi/Klo (swizzled rows) + Vhi/Vlo transposed ----
        {
            const size_t kbase = base + (size_t)(kt * 64) * HD;
            #pragma unroll
            for (int i = 0; i < 2; ++i) {
                const int c = tid + i * 256;
                const int krow = c >> 3;
                const int d0 = (c & 7) * 8;
                const int swzk = (krow & 7) << 4;
                const size_t goff = kbase + (size_t)krow * HD + d0;
                const uint4 hk = *(const uint4*)(khi_g + goff);
                const uint4 lk = *(const uint4*)(klo_g + goff);
                *(uint4*)(smem + KHI_OFF + krow * 128 + ((d0 * 2) ^ swzk)) = hk;
                *(uint4*)(smem + KLO_OFF + krow * 128 + ((d0 * 2) ^ swzk)) = lk;
                const uint4 hv = *(const uint4*)(vhi_g + goff);
                const uint4 lv = *(const uint4*)(vlo_g + goff);
                const unsigned short* he = (const unsigned short*)&hv;
                const unsigned short* le = (const unsigned short*)&lv;
                #pragma unroll
                for (int j = 0; j < 8; ++j) {
                    const int d = d0 + j;
                    const int swzv = (((d >> 3) ^ d) & 7) << 4;
                    const int boff = d * 128 + ((2 * krow) ^ swzv);
                    *(unsigned short*)(smem + VTHI_OFF + boff) = he[j];
                    *(unsigned short*)(smem + VTLO_OFF + boff) = le[j];
                }
            }
        }
        __syncthreads();

        // ---- QK^T: bf16x3 (QhiKhi + QloKhi + QhiKlo) ----
        f32x4 sc[4];
        __builtin_amdgcn_s_setprio(1);        // T5: favor MFMA-issuing wave
        #pragma unroll
        for (int kb = 0; kb < 4; ++kb) {
            f32x4 a = (f32x4){0.f, 0.f, 0.f, 0.f};
            #pragma unroll
            for (int ks = 0; ks < 2; ++ks) {
                const int row = kb * 16 + lm;
                const int cb = 64 * ks + 16 * lg;
                const int swz = (row & 7) << 4;
                const bf16x8 bh_ = *(const bf16x8*)(smem + KHI_OFF + row * 128 + (cb ^ swz));
                const bf16x8 bl_ = *(const bf16x8*)(smem + KLO_OFF + row * 128 + (cb ^ swz));
                a = mfma16(qh[ks], bh_, a);
                a = mfma16(ql[ks], bh_, a);
                a = mfma16(qh[ks], bl_, a);
            }
            sc[kb] = a;
        }
        __builtin_amdgcn_s_setprio(0);

        // ---- scale + causal mask + online softmax (D layout: row=lg*4+r, col=lm) ----
        const bool diag = (kt == qt);
        float tmax[4] = {-1e30f, -1e30f, -1e30f, -1e30f};
        #pragma unroll
        for (int kb = 0; kb < 4; ++kb) {
            const int key = kt * 64 + kb * 16 + lm;
            #pragma unroll
            for (int r = 0; r < 4; ++r) {
                float v = sc[kb][r] * 0.125f;       // 1/sqrt(64)
                const int row = s0 + w * 16 + lg * 4 + r;
                if (diag && key > row) v = -1e30f;
                sc[kb][r] = v;
                tmax[r] = fmaxf(tmax[r], v);
            }
        }
        #pragma unroll
        for (int mk = 1; mk < 16; mk <<= 1)
            #pragma unroll
            for (int r = 0; r < 4; ++r)
                tmax[r] = fmaxf(tmax[r], __shfl_xor(tmax[r], mk));

        float tsum[4], sscale[4];
        #pragma unroll
        for (int r = 0; r < 4; ++r) {
            const float mn = fmaxf(m[r], tmax[r]);
            sscale[r] = __expf(m[r] - mn);
            m[r] = mn;
            float ssum = 0.f;
            #pragma unroll
            for (int kb = 0; kb < 4; ++kb) {
                const float p = __expf(sc[kb][r] - mn);
                sc[kb][r] = p;
                ssum += p;
            }
            tsum[r] = ssum;
        }
        #pragma unroll
        for (int mk = 1; mk < 16; mk <<= 1)
            #pragma unroll
            for (int r = 0; r < 4; ++r)
                tsum[r] += __shfl_xor(tsum[r], mk);

        #pragma unroll
        for (int r = 0; r < 4; ++r) {
            lsum[r] = lsum[r] * sscale[r] + tsum[r];
            #pragma unroll
            for (int dt = 0; dt < 4; ++dt) accO[dt][r] *= sscale[r];
            const int r_loc = lg * 4 + r;
            const int swz = (r_loc & 7) << 4;
            #pragma unroll
            for (int kb = 0; kb < 4; ++kb) {
                const float p = sc[kb][r];
                const unsigned short phq = f2bf(p);
                const unsigned short plq = f2bf(p - bf2f(phq));
                const int boff = (w << 11) + r_loc * 128 + ((2 * (kb * 16 + lm)) ^ swz);
                *(unsigned short*)(smem + PSHI_OFF + boff) = phq;
                *(unsigned short*)(smem + PSLO_OFF + boff) = plq;
            }
        }

        // ---- P @ V: bf16x3 (PhiVhi + PloVhi + PhiVlo) ----
        __builtin_amdgcn_s_setprio(1);        // T5
        #pragma unroll
        for (int ks = 0; ks < 2; ++ks) {
            const int cb = 64 * ks + 16 * lg;
            const int swzp = (lm & 7) << 4;
            const bf16x8 phi = *(const bf16x8*)(smem + PSHI_OFF + (w << 11) + lm * 128 + (cb ^ swzp));
            const bf16x8 plo = *(const bf16x8*)(smem + PSLO_OFF + (w << 11) + lm * 128 + (cb ^ swzp));
            #pragma unroll
            for (int dt = 0; dt < 4; ++dt) {
                const int d = dt * 16 + lm;
                const int swzv = (((d >> 3) ^ d) & 7) << 4;
                const bf16x8 vh_ = *(const bf16x8*)(smem + VTHI_OFF + d * 128 + (cb ^ swzv));
                const bf16x8 vl_ = *(const bf16x8*)(smem + VTLO_OFF + d * 128 + (cb ^ swzv));
                accO[dt] = mfma16(phi, vh_, accO[dt]);
                accO[dt] = mfma16(plo, vh_, accO[dt]);
                accO[dt] = mfma16(phi, vl_, accO[dt]);
            }
        }
        __builtin_amdgcn_s_setprio(0);
    }

    // ---- normalize, LDS transpose (reuse staging region), coalesced store ----
    __syncthreads();
    float* Ot = (float*)smem;                 // [64][66] fp32 = 16896 B
    float invl[4];
    #pragma unroll
    for (int r = 0; r < 4; ++r) invl[r] = 1.0f / lsum[r];
    #pragma unroll
    for (int dt = 0; dt < 4; ++dt)
        #pragma unroll
        for (int r = 0; r < 4; ++r)
            Ot[(w * 16 + lg * 4 + r) * 66 + dt * 16 + lm] = accO[dt][r] * invl[r];
    __syncthreads();
    float* op = out + ((size_t)b * KDIM + (size_t)h * HD) * S + s0;
    #pragma unroll
    for (int i = 0; i < 16; ++i) {
        const int lin = tid + i * 256;
        const int d = lin >> 6, s = lin & 63;
        op[(size_t)d * S + s] = Ot[s * 66 + d];
    }
}

extern "C" void kernel_launch(void* const* d_in, const int* in_sizes, int n_in,
                              void* d_out, int out_size, void* d_ws, size_t ws_size,
                              hipStream_t stream)
{
    const float* input = (const float*)d_in[0];
    const float* q_w   = (const float*)d_in[1];
    const float* q_b   = (const float*)d_in[2];
    const float* k_w   = (const float*)d_in[3];
    const float* k_b   = (const float*)d_in[4];
    const float* v_w   = (const float*)d_in[5];
    const float* v_b   = (const float*)d_in[6];
    float* out = (float*)d_out;

    const size_t per = (size_t)BATCH * NH * S * HD;   // 4,194,304 elems
    unsigned short* qhi = (unsigned short*)d_ws;
    unsigned short* qlo = qhi + per;
    unsigned short* khi = qlo + per;
    unsigned short* klo = khi + per;
    unsigned short* vhi = klo + per;
    unsigned short* vlo = vhi + per;                  // total 48 MB (validated)

    proj_mfma_kernel<<<dim3(8, 12, BATCH), 256, 0, stream>>>(
        input, q_w, q_b, k_w, k_b, v_w, v_b, qhi, qlo, khi, klo, vhi, vlo);

    attn_mfma_kernel<<<dim3(S / 64, NH, BATCH), 256, 0, stream>>>(
        qhi, qlo, khi, klo, vhi, vlo, out);
}

// Round 10
// 195.950 us; speedup vs baseline: 2.7049x; 1.0491x over previous
//
#include <hip/hip_runtime.h>
#include <math.h>

#define BATCH 8
#define CIN 256
#define S 1024       // 32*32 tokens
#define KDIM 512
#define NH 8
#define HD 64        // head dim

typedef float  f32x4  __attribute__((ext_vector_type(4)));
typedef short  bf16x8 __attribute__((ext_vector_type(8)));
typedef unsigned short u16x8 __attribute__((ext_vector_type(8)));

static __device__ __forceinline__ unsigned short f2bf(float x) {
    unsigned u = __builtin_bit_cast(unsigned, x);
    u += 0x7FFFu + ((u >> 16) & 1u);          // RNE
    return (unsigned short)(u >> 16);
}
static __device__ __forceinline__ float bf2f(unsigned short v) {
    unsigned u = ((unsigned)v) << 16;
    return __builtin_bit_cast(float, u);
}
static __device__ __forceinline__ f32x4 mfma16(bf16x8 a, bf16x8 b, f32x4 c) {
    return __builtin_amdgcn_mfma_f32_16x16x32_bf16(a, b, c, 0, 0, 0);
}

// ---------------------------------------------------------------------------
// convert_x: x[b][c][s] f32 -> xt_hi/lo [b][kb=c/32][s][cc=c%32] bf16 (tiled
// so a wave's proj A-fragment read = 1KB contiguous). LDS transpose, pad 132.
// grid (8 s-tiles, 8 kb, B), 256 thr.
// ---------------------------------------------------------------------------
__global__ __launch_bounds__(256)
void convert_x_kernel(const float* __restrict__ in,
                      unsigned short* __restrict__ xt_hi,
                      unsigned short* __restrict__ xt_lo)
{
    __shared__ unsigned short Hs[32][132];
    __shared__ unsigned short Ls[32][132];
    const int s0 = blockIdx.x * 128;
    const int kb = blockIdx.y;
    const int b  = blockIdx.z;
    const int tid = threadIdx.x;
    const float* src = in + ((size_t)b * CIN + kb * 32) * S;
    #pragma unroll
    for (int it = 0; it < 16; ++it) {
        const int lin = it * 256 + tid;
        const int c = lin >> 7;          // 0..31
        const int s = lin & 127;         // coalesced along s
        const float v = src[(size_t)c * S + s0 + s];
        const unsigned short h = f2bf(v);
        Hs[c][s] = h;
        Ls[c][s] = f2bf(v - bf2f(h));
    }
    __syncthreads();
    const size_t obase = ((size_t)b * 8 + kb) * (size_t)S * 32;
    #pragma unroll
    for (int it = 0; it < 2; ++it) {
        const int lin = it * 256 + tid;
        const int j = lin >> 2;          // s-row 0..127
        const int q = lin & 3;           // c-quarter
        u16x8 hv, lv;
        #pragma unroll
        for (int e = 0; e < 8; ++e) {
            hv[e] = Hs[q * 8 + e][j];
            lv[e] = Ls[q * 8 + e][j];
        }
        const size_t o = obase + (size_t)(s0 + j) * 32 + q * 8;
        *(u16x8*)(xt_hi + o) = hv;       // consecutive tid -> contiguous out
        *(u16x8*)(xt_lo + o) = lv;
    }
}

// ---------------------------------------------------------------------------
// convert_w: q_w/k_w/v_w [512][256] f32 -> wt_hi/lo [p][kb][n][32] bf16.
// One thread per 8 c-elems; 192 blocks x 256 thr.
// ---------------------------------------------------------------------------
__global__ __launch_bounds__(256)
void convert_w_kernel(const float* __restrict__ q_w, const float* __restrict__ k_w,
                      const float* __restrict__ v_w,
                      unsigned short* __restrict__ wt_hi,
                      unsigned short* __restrict__ wt_lo)
{
    const int t = blockIdx.x * 256 + threadIdx.x;   // 0..49151
    const int n1536 = t >> 5;
    const int c0 = (t & 31) * 8;
    const int p = n1536 >> 9;
    const int n = n1536 & 511;
    const int kb = c0 >> 5;
    const int cc = c0 & 31;
    const float* w = (p == 0) ? q_w : (p == 1) ? k_w : v_w;
    const float* src = w + (size_t)n * CIN + c0;
    const float4 a = *(const float4*)src;
    const float4 bq = *(const float4*)(src + 4);
    const float vv[8] = {a.x, a.y, a.z, a.w, bq.x, bq.y, bq.z, bq.w};
    u16x8 hv, lv;
    #pragma unroll
    for (int e = 0; e < 8; ++e) {
        const unsigned short h = f2bf(vv[e]);
        hv[e] = h;
        lv[e] = f2bf(vv[e] - bf2f(h));
    }
    const size_t o = ((size_t)((p * 8 + kb) * 512 + n)) * 32 + cc;
    *(u16x8*)(wt_hi + o) = hv;
    *(u16x8*)(wt_lo + o) = lv;
}

// ---------------------------------------------------------------------------
// proj v2: LDS-free, barrier-free MFMA GEMM. bf16x3 on both operands.
// Fragments loaded directly from pre-tiled global (wave read = 1KB contig,
// L2/L3-resident). grid (8, 12, B), 256 thr = 4 waves (2m x 2n), wave 64x64.
// Epilogue (validated round-8 code): bias + hi/lo split -> q/k/v [b][h][s][d].
// ---------------------------------------------------------------------------
__global__ __launch_bounds__(256)
void proj_mfma_kernel(const unsigned short* __restrict__ xt_hi,
                      const unsigned short* __restrict__ xt_lo,
                      const unsigned short* __restrict__ wt_hi,
                      const unsigned short* __restrict__ wt_lo,
                      const float* __restrict__ q_b, const float* __restrict__ k_b,
                      const float* __restrict__ v_b,
                      unsigned short* __restrict__ qhi, unsigned short* __restrict__ qlo,
                      unsigned short* __restrict__ khi, unsigned short* __restrict__ klo,
                      unsigned short* __restrict__ vhi, unsigned short* __restrict__ vlo)
{
    const int s0  = blockIdx.x * 128;
    const int nt  = blockIdx.y;              // 0..11
    const int b   = blockIdx.z;
    const int p   = nt >> 2;                 // 0=q,1=k,2=v
    const int nb0 = (nt & 3) * 128;

    const float* bs = (p == 0) ? q_b : (p == 1) ? k_b : v_b;
    unsigned short* ph_g = (p == 0) ? qhi : (p == 1) ? khi : vhi;
    unsigned short* pl_g = (p == 0) ? qlo : (p == 1) ? klo : vlo;

    const int tid = threadIdx.x;
    const int wv  = tid >> 6;
    const int wm  = wv >> 1, wn = wv & 1;
    const int l   = tid & 63;
    const int lg  = l >> 4;
    const int lm  = l & 15;

    f32x4 acc[4][4];
    #pragma unroll
    for (int mf = 0; mf < 4; ++mf)
        #pragma unroll
        for (int nf = 0; nf < 4; ++nf) acc[mf][nf] = (f32x4){0.f, 0.f, 0.f, 0.f};

    for (int kb = 0; kb < 8; ++kb) {
        // A frags: row = s0 + wm*64 + mf*16 + lm, k = lg*8 + e  (16B contig)
        const size_t aoff = ((size_t)(b * 8 + kb) * S + (s0 + wm * 64 + lm)) * 32 + lg * 8;
        bf16x8 ah[4], al[4];
        #pragma unroll
        for (int mf = 0; mf < 4; ++mf) {
            ah[mf] = *(const bf16x8*)(xt_hi + aoff + (size_t)mf * 512);
            al[mf] = *(const bf16x8*)(xt_lo + aoff + (size_t)mf * 512);
        }
        const size_t boff = ((size_t)((p * 8 + kb) * 512) + (nb0 + wn * 64 + lm)) * 32 + lg * 8;
        __builtin_amdgcn_s_setprio(1);
        #pragma unroll
        for (int nf = 0; nf < 4; ++nf) {
            const bf16x8 bh = *(const bf16x8*)(wt_hi + boff + (size_t)nf * 512);
            const bf16x8 bl = *(const bf16x8*)(wt_lo + boff + (size_t)nf * 512);
            #pragma unroll
            for (int mf = 0; mf < 4; ++mf) {
                acc[mf][nf] = mfma16(ah[mf], bh, acc[mf][nf]);
                acc[mf][nf] = mfma16(al[mf], bh, acc[mf][nf]);
                acc[mf][nf] = mfma16(ah[mf], bl, acc[mf][nf]);
            }
        }
        __builtin_amdgcn_s_setprio(0);
    }

    #pragma unroll
    for (int nf = 0; nf < 4; ++nf) {
        const int ncol = nb0 + wn * 64 + nf * 16 + lm;
        const int h = ncol >> 6, d = ncol & 63;
        const float bias = bs[ncol];
        const size_t hb = ((size_t)b * NH + h) * S * HD + d;
        #pragma unroll
        for (int mf = 0; mf < 4; ++mf) {
            #pragma unroll
            for (int r = 0; r < 4; ++r) {
                const int srow = s0 + wm * 64 + mf * 16 + lg * 4 + r;
                const float x = acc[mf][nf][r] + bias;
                const unsigned short hq = f2bf(x);
                const unsigned short lq = f2bf(x - bf2f(hq));
                ph_g[hb + (size_t)srow * HD] = hq;
                pl_g[hb + (size_t)srow * HD] = lq;
            }
        }
    }
}

// ---------------------------------------------------------------------------
// attn v2: validated bf16x3 compute (byte-identical math), plus:
//  - balanced causal pairing: block bx does qt=bx then qt=15-bx (17 tiles each)
//  - T14 async-stage split: next tile's K/V global loads issued after the LDS
//    write phase, landing under current tile's QK/softmax/PV.
// ---------------------------------------------------------------------------
#define KHI_OFF  0
#define KLO_OFF  8192
#define VTHI_OFF 16384
#define VTLO_OFF 24576
#define PSHI_OFF 32768   // + w*2048
#define PSLO_OFF 40960   // + w*2048

__global__ __launch_bounds__(256)
void attn_mfma_kernel(const unsigned short* __restrict__ qhi_g,
                      const unsigned short* __restrict__ qlo_g,
                      const unsigned short* __restrict__ khi_g,
                      const unsigned short* __restrict__ klo_g,
                      const unsigned short* __restrict__ vhi_g,
                      const unsigned short* __restrict__ vlo_g,
                      float* __restrict__ out)
{
    __shared__ __attribute__((aligned(16))) char smem[49152];

    const int bx = blockIdx.x;               // 0..7
    const int h  = blockIdx.y;
    const int b  = blockIdx.z;
    const int tid = threadIdx.x;
    const int w  = tid >> 6;
    const int l  = tid & 63;
    const int lg = l >> 4;
    const int lm = l & 15;

    const size_t base = ((size_t)b * NH + h) * S * HD;

    for (int pi = 0; pi < 2; ++pi) {
        const int qt = pi ? 15 - bx : bx;
        const int s0 = qt * 64;

        // Q fragments: row = s0 + w*16 + lm, k = ks*32 + lg*8 (+0..7)
        bf16x8 qh[2], ql[2];
        {
            const size_t qoff = base + (size_t)(s0 + w * 16 + lm) * HD + lg * 8;
            qh[0] = *(const bf16x8*)(qhi_g + qoff);
            qh[1] = *(const bf16x8*)(qhi_g + qoff + 32);
            ql[0] = *(const bf16x8*)(qlo_g + qoff);
            ql[1] = *(const bf16x8*)(qlo_g + qoff + 32);
        }

        float m[4] = {-1e30f, -1e30f, -1e30f, -1e30f};
        float lsum[4] = {0.f, 0.f, 0.f, 0.f};
        f32x4 accO[4];
        #pragma unroll
        for (int dt = 0; dt < 4; ++dt) accO[dt] = (f32x4){0.f, 0.f, 0.f, 0.f};

        // prologue: stage tile kt=0 into registers
        uint4 hk[2], lk[2], hv[2], lv[2];
        #pragma unroll
        for (int i = 0; i < 2; ++i) {
            const int c = tid + i * 256;
            const int krow = c >> 3;
            const int d0 = (c & 7) * 8;
            const size_t goff = base + (size_t)krow * HD + d0;
            hk[i] = *(const uint4*)(khi_g + goff);
            lk[i] = *(const uint4*)(klo_g + goff);
            hv[i] = *(const uint4*)(vhi_g + goff);
            lv[i] = *(const uint4*)(vlo_g + goff);
        }

        for (int kt = 0; kt <= qt; ++kt) {
            __syncthreads();                  // all waves done with prev LDS use
            // ---- write staged regs -> LDS (swizzled K, transposed V) ----
            #pragma unroll
            for (int i = 0; i < 2; ++i) {
                const int c = tid + i * 256;
                const int krow = c >> 3;
                const int d0 = (c & 7) * 8;
                const int swzk = (krow & 7) << 4;
                *(uint4*)(smem + KHI_OFF + krow * 128 + ((d0 * 2) ^ swzk)) = hk[i];
                *(uint4*)(smem + KLO_OFF + krow * 128 + ((d0 * 2) ^ swzk)) = lk[i];
                const unsigned short* he = (const unsigned short*)&hv[i];
                const unsigned short* le = (const unsigned short*)&lv[i];
                #pragma unroll
                for (int j = 0; j < 8; ++j) {
                    const int d = d0 + j;
                    const int swzv = (((d >> 3) ^ d) & 7) << 4;
                    const int boff = d * 128 + ((2 * krow) ^ swzv);
                    *(unsigned short*)(smem + VTHI_OFF + boff) = he[j];
                    *(unsigned short*)(smem + VTLO_OFF + boff) = le[j];
                }
            }
            // ---- T14: issue next tile's global loads (land under compute) ----
            if (kt < qt) {
                const size_t kbase = base + (size_t)((kt + 1) * 64) * HD;
                #pragma unroll
                for (int i = 0; i < 2; ++i) {
                    const int c = tid + i * 256;
                    const int krow = c >> 3;
                    const int d0 = (c & 7) * 8;
                    const size_t goff = kbase + (size_t)krow * HD + d0;
                    hk[i] = *(const uint4*)(khi_g + goff);
                    lk[i] = *(const uint4*)(klo_g + goff);
                    hv[i] = *(const uint4*)(vhi_g + goff);
                    lv[i] = *(const uint4*)(vlo_g + goff);
                }
            }
            __syncthreads();                  // staged LDS visible to all

            // ---- QK^T: bf16x3 ----
            f32x4 sc[4];
            __builtin_amdgcn_s_setprio(1);
            #pragma unroll
            for (int kb = 0; kb < 4; ++kb) {
                f32x4 a = (f32x4){0.f, 0.f, 0.f, 0.f};
                #pragma unroll
                for (int ks = 0; ks < 2; ++ks) {
                    const int row = kb * 16 + lm;
                    const int cb = 64 * ks + 16 * lg;
                    const int swz = (row & 7) << 4;
                    const bf16x8 bh_ = *(const bf16x8*)(smem + KHI_OFF + row * 128 + (cb ^ swz));
                    const bf16x8 bl_ = *(const bf16x8*)(smem + KLO_OFF + row * 128 + (cb ^ swz));
                    a = mfma16(qh[ks], bh_, a);
                    a = mfma16(ql[ks], bh_, a);
                    a = mfma16(qh[ks], bl_, a);
                }
                sc[kb] = a;
            }
            __builtin_amdgcn_s_setprio(0);

            // ---- scale + causal mask + online softmax ----
            const bool diag = (kt == qt);
            float tmax[4] = {-1e30f, -1e30f, -1e30f, -1e30f};
            #pragma unroll
            for (int kb = 0; kb < 4; ++kb) {
                const int key = kt * 64 + kb * 16 + lm;
                #pragma unroll
                for (int r = 0; r < 4; ++r) {
                    float v = sc[kb][r] * 0.125f;       // 1/sqrt(64)
                    const int row = s0 + w * 16 + lg * 4 + r;
                    if (diag && key > row) v = -1e30f;
                    sc[kb][r] = v;
                    tmax[r] = fmaxf(tmax[r], v);
                }
            }
            #pragma unroll
            for (int mk = 1; mk < 16; mk <<= 1)
                #pragma unroll
                for (int r = 0; r < 4; ++r)
                    tmax[r] = fmaxf(tmax[r], __shfl_xor(tmax[r], mk));

            float tsum[4], sscale[4];
            #pragma unroll
            for (int r = 0; r < 4; ++r) {
                const float mn = fmaxf(m[r], tmax[r]);
                sscale[r] = __expf(m[r] - mn);
                m[r] = mn;
                float ssum = 0.f;
                #pragma unroll
                for (int kb = 0; kb < 4; ++kb) {
                    const float p = __expf(sc[kb][r] - mn);
                    sc[kb][r] = p;
                    ssum += p;
                }
                tsum[r] = ssum;
            }
            #pragma unroll
            for (int mk = 1; mk < 16; mk <<= 1)
                #pragma unroll
                for (int r = 0; r < 4; ++r)
                    tsum[r] += __shfl_xor(tsum[r], mk);

            #pragma unroll
            for (int r = 0; r < 4; ++r) {
                lsum[r] = lsum[r] * sscale[r] + tsum[r];
                #pragma unroll
                for (int dt = 0; dt < 4; ++dt) accO[dt][r] *= sscale[r];
                const int r_loc = lg * 4 + r;
                const int swz = (r_loc & 7) << 4;
                #pragma unroll
                for (int kb = 0; kb < 4; ++kb) {
                    const float p = sc[kb][r];
                    const unsigned short phq = f2bf(p);
                    const unsigned short plq = f2bf(p - bf2f(phq));
                    const int boff = (w << 11) + r_loc * 128 + ((2 * (kb * 16 + lm)) ^ swz);
                    *(unsigned short*)(smem + PSHI_OFF + boff) = phq;
                    *(unsigned short*)(smem + PSLO_OFF + boff) = plq;
                }
            }

            // ---- P @ V: bf16x3 ----
            __builtin_amdgcn_s_setprio(1);
            #pragma unroll
            for (int ks = 0; ks < 2; ++ks) {
                const int cb = 64 * ks + 16 * lg;
                const int swzp = (lm & 7) << 4;
                const bf16x8 phi = *(const bf16x8*)(smem + PSHI_OFF + (w << 11) + lm * 128 + (cb ^ swzp));
                const bf16x8 plo = *(const bf16x8*)(smem + PSLO_OFF + (w << 11) + lm * 128 + (cb ^ swzp));
                #pragma unroll
                for (int dt = 0; dt < 4; ++dt) {
                    const int d = dt * 16 + lm;
                    const int swzv = (((d >> 3) ^ d) & 7) << 4;
                    const bf16x8 vh_ = *(const bf16x8*)(smem + VTHI_OFF + d * 128 + (cb ^ swzv));
                    const bf16x8 vl_ = *(const bf16x8*)(smem + VTLO_OFF + d * 128 + (cb ^ swzv));
                    accO[dt] = mfma16(phi, vh_, accO[dt]);
                    accO[dt] = mfma16(plo, vh_, accO[dt]);
                    accO[dt] = mfma16(phi, vl_, accO[dt]);
                }
            }
            __builtin_amdgcn_s_setprio(0);
        }

        // ---- normalize, LDS transpose, coalesced store ----
        __syncthreads();
        float* Ot = (float*)smem;             // [64][66] fp32, reuses staging
        float invl[4];
        #pragma unroll
        for (int r = 0; r < 4; ++r) invl[r] = 1.0f / lsum[r];
        #pragma unroll
        for (int dt = 0; dt < 4; ++dt)
            #pragma unroll
            for (int r = 0; r < 4; ++r)
                Ot[(w * 16 + lg * 4 + r) * 66 + dt * 16 + lm] = accO[dt][r] * invl[r];
        __syncthreads();
        float* op = out + ((size_t)b * KDIM + (size_t)h * HD) * S + s0;
        #pragma unroll
        for (int i = 0; i < 16; ++i) {
            const int lin = tid + i * 256;
            const int d = lin >> 6, s = lin & 63;
            op[(size_t)d * S + s] = Ot[s * 66 + d];
        }
        __syncthreads();                      // Ot reads done before next pass stages
    }
}

extern "C" void kernel_launch(void* const* d_in, const int* in_sizes, int n_in,
                              void* d_out, int out_size, void* d_ws, size_t ws_size,
                              hipStream_t stream)
{
    const float* input = (const float*)d_in[0];
    const float* q_w   = (const float*)d_in[1];
    const float* q_b   = (const float*)d_in[2];
    const float* k_w   = (const float*)d_in[3];
    const float* k_b   = (const float*)d_in[4];
    const float* v_w   = (const float*)d_in[5];
    const float* v_b   = (const float*)d_in[6];
    float* out = (float*)d_out;

    const size_t per = (size_t)BATCH * NH * S * HD;   // 4,194,304 elems
    unsigned short* qhi = (unsigned short*)d_ws;      // ws: 6 x 8MB = 48MB (validated)
    unsigned short* qlo = qhi + per;
    unsigned short* khi = qlo + per;
    unsigned short* klo = khi + per;
    unsigned short* vhi = klo + per;
    unsigned short* vlo = vhi + per;

    // d_out doubles as scratch for the converted inputs (9.5MB < 16MB); it is
    // fully overwritten by attn afterwards (convert -> proj -> attn in order).
    unsigned short* xt_hi = (unsigned short*)d_out;                 // 4MB
    unsigned short* xt_lo = xt_hi + (size_t)BATCH * CIN * S;        // 4MB
    unsigned short* wt_hi = xt_lo + (size_t)BATCH * CIN * S;        // 0.75MB
    unsigned short* wt_lo = wt_hi + (size_t)3 * KDIM * CIN;         // 0.75MB

    convert_x_kernel<<<dim3(8, 8, BATCH), 256, 0, stream>>>(input, xt_hi, xt_lo);
    convert_w_kernel<<<dim3(192, 1, 1), 256, 0, stream>>>(q_w, k_w, v_w, wt_hi, wt_lo);

    proj_mfma_kernel<<<dim3(8, 12, BATCH), 256, 0, stream>>>(
        xt_hi, xt_lo, wt_hi, wt_lo, q_b, k_b, v_b,
        qhi, qlo, khi, klo, vhi, vlo);

    attn_mfma_kernel<<<dim3(8, NH, BATCH), 256, 0, stream>>>(
        qhi, qlo, khi, klo, vhi, vlo, out);
}